// Round 4
// baseline (605.146 us; speedup 1.0000x reference)
//
#include <hip/hip_runtime.h>

#define NN     10000
#define HEADS  8
#define HID    64
#define ODIM   5000
#define NE     160000
#define ET     170000   // NE + NN self-loops
#define NEG    0.2f
#define WT_LD  5120     // padded leading dim of transposed fc_w
#define TRB    79       // ceil(ODIM/64) transpose blocks
#define DEGB   40       // ceil(NN/256) deg-init blocks
#define PREPB  (TRB + DEGB + 1)
#define FC_R   16       // fc2 rows per block

// -------- edge_index storage-format detection (int32 vs int64 words) --------
__device__ __forceinline__ int ld_idx(const int* ei, int k, int mode) {
    return mode ? ei[2 * k] : ei[k];   // little-endian lo word carries the id
}

// prep: fc_w transpose (blocks 0..TRB-1), deg init (TRB..TRB+DEGB-1), detect (last)
__global__ void __launch_bounds__(256) k_prep(
    const int* __restrict__ ei, int* __restrict__ flag,
    int* __restrict__ deg,
    const float* __restrict__ W, float* __restrict__ Wt) {
    __shared__ float T[64][65];
    __shared__ int nz;
    int bid = blockIdx.x, t = threadIdx.x;
    if (bid < TRB) {
        int c0 = bid * 64;
        int cl = t >> 2, kq = (t & 3) * 16;
        if (c0 + cl < ODIM) {
            #pragma unroll
            for (int q = 0; q < 4; q++) {
                float4 v = *(const float4*)(W + (size_t)(c0 + cl) * 64 + kq + q * 4);
                T[cl][kq + q * 4 + 0] = v.x;
                T[cl][kq + q * 4 + 1] = v.y;
                T[cl][kq + q * 4 + 2] = v.z;
                T[cl][kq + q * 4 + 3] = v.w;
            }
        } else {
            #pragma unroll
            for (int q = 0; q < 16; q++) T[cl][kq + q] = 0.f;   // zero pad cols
        }
        __syncthreads();
        int kl = t >> 2, cq = (t & 3) * 16;
        #pragma unroll
        for (int q = 0; q < 4; q++) {
            float4 v = make_float4(T[cq + q * 4 + 0][kl], T[cq + q * 4 + 1][kl],
                                   T[cq + q * 4 + 2][kl], T[cq + q * 4 + 3][kl]);
            *(float4*)(Wt + (size_t)kl * WT_LD + c0 + cq + q * 4) = v;
        }
    } else if (bid < TRB + DEGB) {
        int i = (bid - TRB) * 256 + t;
        if (i < NN) deg[i] = 1;   // self-loop
    } else {
        if (t == 0) nz = 0;
        __syncthreads();
        int c = 0;
        #pragma unroll
        for (int q = 0; q < 4; q++)
            if (ei[2 * (t * 4 + q) + 1] != 0) c++;
        if (c) atomicAdd(&nz, c);
        __syncthreads();
        if (t == 0) *flag = (nz == 0) ? 1 : 0;
    }
}

// ---------------- CSR build (by dst) ----------------
__global__ void k_hist(const int* __restrict__ ei, const int* __restrict__ flag,
                       int* __restrict__ deg) {
    int e = blockIdx.x * blockDim.x + threadIdx.x;
    if (e < NE) atomicAdd(&deg[ld_idx(ei, NE + e, *flag)], 1);
}

// wave-shuffle scan: 10 chunks x 3 barriers
__global__ void k_scan(const int* __restrict__ deg, int* __restrict__ rowptr,
                       int* __restrict__ cursor) {
    __shared__ int wsum[16];
    __shared__ int carry;
    int t = threadIdx.x, lane = t & 63, wv = t >> 6;
    if (t == 0) carry = 0;
    __syncthreads();
    for (int base = 0; base < NN; base += 1024) {
        int i = base + t;
        int v = (i < NN) ? deg[i] : 0;
        int s = v;
        #pragma unroll
        for (int off = 1; off < 64; off <<= 1) {
            int u = __shfl_up(s, off, 64);
            if (lane >= off) s += u;
        }
        if (lane == 63) wsum[wv] = s;
        __syncthreads();
        if (t == 0) {
            int run = carry;
            #pragma unroll
            for (int j = 0; j < 16; j++) { int tmp = wsum[j]; wsum[j] = run; run += tmp; }
            carry = run;
        }
        __syncthreads();
        if (i < NN) { int ex = wsum[wv] + s - v; rowptr[i] = ex; cursor[i] = ex; }
        __syncthreads();   // protect wsum before next chunk overwrites
    }
    if (t == 0) rowptr[NN] = carry;
}

__global__ void k_scatter(const int* __restrict__ ei, const int* __restrict__ flag,
                          int* __restrict__ cursor, int* __restrict__ csr) {
    int e = blockIdx.x * blockDim.x + threadIdx.x;
    if (e < NE) {
        int mode = *flag;
        int d = ld_idx(ei, NE + e, mode);
        int pos = atomicAdd(&cursor[d], 1);
        csr[pos] = ld_idx(ei, e, mode);
    } else if (e < ET) {
        int n = e - NE;
        int pos = atomicAdd(&cursor[n], 1);
        csr[pos] = n;   // self-loop src == dst
    }
}

// ---- layer-1 pair GEMM: 64x64 tile, 128 threads, 8x4 per-thread per matrix ----
// Per k-step: 4 ds_read_b128 (64B) feed 64 FMAs -> LDS demand ~70us vs FMA ~80us
// (old config: 48B per 32 FMA -> LDS-bound at 153us, VALUBusy 56%).
// Reads conflict-free: A broadcast over 16-lane groups; W 2-way (free, m136).
// Staging writes row=t>>1 -> 2 lanes/bank (free).
__global__ void __launch_bounds__(128) k_gemm12_big(
    const float* __restrict__ A,
    const float* __restrict__ Wl, const float* __restrict__ bl,
    const float* __restrict__ Wr, const float* __restrict__ br,
    float* __restrict__ Cl, float* __restrict__ Cr,
    int M, int Ndim, int K) {
    __shared__ float As[32][64];
    __shared__ float Ls[32][64];
    __shared__ float Rs[32][64];
    int t = threadIdx.x;
    int m0 = blockIdx.x * 64, n0 = blockIdx.y * 64;
    int tx = t & 15, ty = t >> 4;        // ty 0..7 -> 8 rows each
    int srow = t >> 1, skc = (t & 1) * 16;
    int rowA = m0 + srow, rowW = n0 + srow;
    float accL[8][4] = {}, accR[8][4] = {};
    for (int kt = 0; kt < K; kt += 32) {
        float4 a[4], l[4], r[4];
        if (rowA < M) {
            const float* ap = A + (size_t)rowA * K + kt + skc;
            #pragma unroll
            for (int q = 0; q < 4; q++) a[q] = *(const float4*)(ap + q * 4);
        } else {
            #pragma unroll
            for (int q = 0; q < 4; q++) a[q] = make_float4(0.f, 0.f, 0.f, 0.f);
        }
        const float* lp = Wl + (size_t)rowW * K + kt + skc;
        const float* rp = Wr + (size_t)rowW * K + kt + skc;
        #pragma unroll
        for (int q = 0; q < 4; q++) l[q] = *(const float4*)(lp + q * 4);
        #pragma unroll
        for (int q = 0; q < 4; q++) r[q] = *(const float4*)(rp + q * 4);
        __syncthreads();   // previous iteration's reads complete before overwrite
        #pragma unroll
        for (int q = 0; q < 4; q++) {
            int k = skc + q * 4;
            As[k + 0][srow] = a[q].x; As[k + 1][srow] = a[q].y;
            As[k + 2][srow] = a[q].z; As[k + 3][srow] = a[q].w;
            Ls[k + 0][srow] = l[q].x; Ls[k + 1][srow] = l[q].y;
            Ls[k + 2][srow] = l[q].z; Ls[k + 3][srow] = l[q].w;
            Rs[k + 0][srow] = r[q].x; Rs[k + 1][srow] = r[q].y;
            Rs[k + 2][srow] = r[q].z; Rs[k + 3][srow] = r[q].w;
        }
        __syncthreads();
        #pragma unroll
        for (int k = 0; k < 32; k++) {
            float4 a0 = *(const float4*)&As[k][ty * 8];
            float4 a1 = *(const float4*)&As[k][ty * 8 + 4];
            float4 lv = *(const float4*)&Ls[k][tx * 4];
            float4 rv = *(const float4*)&Rs[k][tx * 4];
            float ar[8] = {a0.x, a0.y, a0.z, a0.w, a1.x, a1.y, a1.z, a1.w};
            float lb[4] = {lv.x, lv.y, lv.z, lv.w};
            float rb[4] = {rv.x, rv.y, rv.z, rv.w};
            #pragma unroll
            for (int i = 0; i < 8; i++)
                #pragma unroll
                for (int j = 0; j < 4; j++) {
                    accL[i][j] = fmaf(ar[i], lb[j], accL[i][j]);
                    accR[i][j] = fmaf(ar[i], rb[j], accR[i][j]);
                }
        }
    }
    int col0 = n0 + tx * 4;
    float4 bvl = *(const float4*)&bl[col0];
    float4 bvr = *(const float4*)&br[col0];
    #pragma unroll
    for (int i = 0; i < 8; i++) {
        int rr = m0 + ty * 8 + i;
        if (rr < M) {
            float4 ol = make_float4(accL[i][0] + bvl.x, accL[i][1] + bvl.y,
                                    accL[i][2] + bvl.z, accL[i][3] + bvl.w);
            float4 orr = make_float4(accR[i][0] + bvr.x, accR[i][1] + bvr.y,
                                     accR[i][2] + bvr.z, accR[i][3] + bvr.w);
            *(float4*)&Cl[(size_t)rr * Ndim + col0] = ol;
            *(float4*)&Cr[(size_t)rr * Ndim + col0] = orr;
        }
    }
}

// ---- layer-2 pair GEMM (N=64, small): 64x64 tile, 256 thr, 4x4/thread ----
__global__ void __launch_bounds__(256) k_gemm12(
    const float* __restrict__ A,
    const float* __restrict__ Wl, const float* __restrict__ bl,
    const float* __restrict__ Wr, const float* __restrict__ br,
    float* __restrict__ Cl, float* __restrict__ Cr,
    int M, int Ndim, int K) {
    __shared__ float As[32][64];
    __shared__ float Ls[32][64];
    __shared__ float Rs[32][64];
    int t = threadIdx.x;
    int m0 = blockIdx.x * 64, n0 = blockIdx.y * 64;
    int lm = t >> 2;
    int kc = (t & 3) * 8;
    int tx = t & 15, ty = t >> 4;
    int rowA = m0 + lm;
    int rowW = n0 + lm;
    float accL[4][4] = {}, accR[4][4] = {};
    for (int kt = 0; kt < K; kt += 32) {
        float av[8];
        if (rowA < M) {
            const float* ap = A + (size_t)rowA * K + kt + kc;
            float4 p0 = *(const float4*)ap;
            float4 p1 = *(const float4*)(ap + 4);
            av[0] = p0.x; av[1] = p0.y; av[2] = p0.z; av[3] = p0.w;
            av[4] = p1.x; av[5] = p1.y; av[6] = p1.z; av[7] = p1.w;
        } else {
            #pragma unroll
            for (int j = 0; j < 8; j++) av[j] = 0.f;
        }
        const float* lp = Wl + (size_t)rowW * K + kt + kc;
        float4 l0 = *(const float4*)lp;
        float4 l1 = *(const float4*)(lp + 4);
        float lv[8] = {l0.x, l0.y, l0.z, l0.w, l1.x, l1.y, l1.z, l1.w};
        const float* rp = Wr + (size_t)rowW * K + kt + kc;
        float4 r0 = *(const float4*)rp;
        float4 r1 = *(const float4*)(rp + 4);
        float rv[8] = {r0.x, r0.y, r0.z, r0.w, r1.x, r1.y, r1.z, r1.w};
        #pragma unroll
        for (int j = 0; j < 8; j++) As[kc + j][lm] = av[j];
        #pragma unroll
        for (int j = 0; j < 8; j++) Ls[kc + j][lm] = lv[j];
        #pragma unroll
        for (int j = 0; j < 8; j++) Rs[kc + j][lm] = rv[j];
        __syncthreads();
        #pragma unroll
        for (int k = 0; k < 32; k++) {
            float4 a4 = *(const float4*)&As[k][ty * 4];
            float4 b4 = *(const float4*)&Ls[k][tx * 4];
            float4 c4 = *(const float4*)&Rs[k][tx * 4];
            float aa[4] = {a4.x, a4.y, a4.z, a4.w};
            float bb[4] = {b4.x, b4.y, b4.z, b4.w};
            float cc[4] = {c4.x, c4.y, c4.z, c4.w};
            #pragma unroll
            for (int i = 0; i < 4; i++)
                #pragma unroll
                for (int j = 0; j < 4; j++) {
                    accL[i][j] = fmaf(aa[i], bb[j], accL[i][j]);
                    accR[i][j] = fmaf(aa[i], cc[j], accR[i][j]);
                }
        }
        __syncthreads();
    }
    int col0 = n0 + tx * 4;
    float4 bvl = *(const float4*)&bl[col0];
    float4 bvr = *(const float4*)&br[col0];
    #pragma unroll
    for (int i = 0; i < 4; i++) {
        int r = m0 + ty * 4 + i;
        if (r < M) {
            float4 ol = make_float4(accL[i][0] + bvl.x, accL[i][1] + bvl.y,
                                    accL[i][2] + bvl.z, accL[i][3] + bvl.w);
            float4 orr = make_float4(accR[i][0] + bvr.x, accR[i][1] + bvr.y,
                                     accR[i][2] + bvr.z, accR[i][3] + bvr.w);
            *(float4*)&Cl[(size_t)r * Ndim + col0] = ol;
            *(float4*)&Cr[(size_t)r * Ndim + col0] = orr;
        }
    }
}

// ------- fused GATv2 layer 1: one wave per node, online softmax -------
__global__ void __launch_bounds__(256) k_gat1(
    const float* __restrict__ xl, const float* __restrict__ xr,
    const float* __restrict__ att, const float* __restrict__ bias,
    const int* __restrict__ rowptr, const int* __restrict__ csr,
    float* __restrict__ out) {
    int wid = (blockIdx.x * blockDim.x + threadIdx.x) >> 6;
    int lane = threadIdx.x & 63;
    if (wid >= NN) return;
    int n = wid;
    int off = lane * 4;            // = (l>>4)*64 + 4*(l&15)
    const float4* xr4  = (const float4*)(xr + (size_t)n * 512 + off);
    const float4* att4 = (const float4*)(att + off);
    float4 xrA = xr4[0],  xrB = xr4[64];    // +256 floats
    float4 atA = att4[0], atB = att4[64];
    float4 accA = make_float4(0.f, 0.f, 0.f, 0.f);
    float4 accB = make_float4(0.f, 0.f, 0.f, 0.f);
    float lA = 0.f, lB = 0.f, mA = -1e30f, mB = -1e30f;

    int p0 = rowptr[n], p1 = rowptr[n + 1];
    int deg = p1 - p0;             // >= 1 (self-loop)
    float4 a0, b0, a1, b1;
    {
        const float4* p = (const float4*)(xl + (size_t)csr[p0] * 512 + off);
        a0 = p[0]; b0 = p[64];
    }
    if (deg > 1) {
        const float4* p = (const float4*)(xl + (size_t)csr[p0 + 1] * 512 + off);
        a1 = p[0]; b1 = p[64];
    } else { a1 = a0; b1 = b0; }
    for (int i = 0; i < deg; i++) {
        float4 cxa = a0, cxb = b0;
        a0 = a1; b0 = b1;
        if (i + 2 < deg) {
            const float4* np = (const float4*)(xl + (size_t)csr[p0 + i + 2] * 512 + off);
            a1 = np[0]; b1 = np[64];
        }
        // leaky(x+xr) . att, 4-channel partials
        float vA0 = cxa.x + xrA.x, vA1 = cxa.y + xrA.y,
              vA2 = cxa.z + xrA.z, vA3 = cxa.w + xrA.w;
        float vB0 = cxb.x + xrB.x, vB1 = cxb.y + xrB.y,
              vB2 = cxb.z + xrB.z, vB3 = cxb.w + xrB.w;
        vA0 = (vA0 > 0.f) ? vA0 : NEG * vA0;  vA1 = (vA1 > 0.f) ? vA1 : NEG * vA1;
        vA2 = (vA2 > 0.f) ? vA2 : NEG * vA2;  vA3 = (vA3 > 0.f) ? vA3 : NEG * vA3;
        vB0 = (vB0 > 0.f) ? vB0 : NEG * vB0;  vB1 = (vB1 > 0.f) ? vB1 : NEG * vB1;
        vB2 = (vB2 > 0.f) ? vB2 : NEG * vB2;  vB3 = (vB3 > 0.f) ? vB3 : NEG * vB3;
        float sA = vA0 * atA.x + vA1 * atA.y + vA2 * atA.z + vA3 * atA.w;
        float sB = vB0 * atB.x + vB1 * atB.y + vB2 * atB.z + vB3 * atB.w;
        #pragma unroll
        for (int m = 1; m <= 8; m <<= 1) {
            sA += __shfl_xor(sA, m, 64);
            sB += __shfl_xor(sB, m, 64);
        }
        // online softmax update, head A
        float mnA = fmaxf(mA, sA);
        float scA = __expf(mA - mnA), peA = __expf(sA - mnA);
        accA.x = accA.x * scA + peA * cxa.x;  accA.y = accA.y * scA + peA * cxa.y;
        accA.z = accA.z * scA + peA * cxa.z;  accA.w = accA.w * scA + peA * cxa.w;
        lA = lA * scA + peA;  mA = mnA;
        // head B
        float mnB = fmaxf(mB, sB);
        float scB = __expf(mB - mnB), peB = __expf(sB - mnB);
        accB.x = accB.x * scB + peB * cxb.x;  accB.y = accB.y * scB + peB * cxb.y;
        accB.z = accB.z * scB + peB * cxb.z;  accB.w = accB.w * scB + peB * cxb.w;
        lB = lB * scB + peB;  mB = mnB;
    }
    float rA = 1.f / (lA + 1e-16f), rB = 1.f / (lB + 1e-16f);
    float4 biA = *(const float4*)(bias + off);
    float4 biB = *(const float4*)(bias + off + 256);
    float4 oA = make_float4(fmaxf(accA.x * rA + biA.x, 0.f),
                            fmaxf(accA.y * rA + biA.y, 0.f),
                            fmaxf(accA.z * rA + biA.z, 0.f),
                            fmaxf(accA.w * rA + biA.w, 0.f));
    float4 oB = make_float4(fmaxf(accB.x * rB + biB.x, 0.f),
                            fmaxf(accB.y * rB + biB.y, 0.f),
                            fmaxf(accB.z * rB + biB.z, 0.f),
                            fmaxf(accB.w * rB + biB.w, 0.f));
    float4* op = (float4*)(out + (size_t)n * 512 + off);
    op[0]  = oA;      // ReLU applied (layer-1 activation)
    op[64] = oB;
}

// ------- fused GATv2 layer 2 (1 head, 64 ch): one wave per node -------
__global__ void __launch_bounds__(256) k_gat2(
    const float* __restrict__ xl, const float* __restrict__ xr,
    const float* __restrict__ att, const float* __restrict__ bias,
    const int* __restrict__ rowptr, const int* __restrict__ csr,
    float* __restrict__ out) {
    int wid = (blockIdx.x * blockDim.x + threadIdx.x) >> 6;
    int lane = threadIdx.x & 63;
    if (wid >= NN) return;
    int n = wid;
    float xrv = xr[(size_t)n * 64 + lane];
    float atv = att[lane];
    float acc = 0.f, lsum = 0.f, mmax = -1e30f;
    int p0 = rowptr[n], p1 = rowptr[n + 1];
    int deg = p1 - p0;
    float x0 = xl[(size_t)csr[p0] * 64 + lane];
    float x1 = (deg > 1) ? xl[(size_t)csr[p0 + 1] * 64 + lane] : x0;
    for (int i = 0; i < deg; i++) {
        float xs = x0;
        x0 = x1;
        if (i + 2 < deg) x1 = xl[(size_t)csr[p0 + i + 2] * 64 + lane];
        float v = xs + xrv;
        v = (v > 0.f) ? v : NEG * v;
        float sc = v * atv;
        #pragma unroll
        for (int off = 32; off > 0; off >>= 1)
            sc += __shfl_xor(sc, off, 64);
        float mn = fmaxf(mmax, sc);
        float scale = __expf(mmax - mn);
        float pe = __expf(sc - mn);
        acc = acc * scale + pe * xs;
        lsum = lsum * scale + pe;
        mmax = mn;
    }
    float o = acc / (lsum + 1e-16f) + bias[lane];
    out[(size_t)n * 64 + lane] = (o > 0.f) ? o : 0.f;   // ReLU after layer 2
}

// --- FC: out[10000,5000] = h2[10000,64] @ Wt + fc_b ---
__global__ void __launch_bounds__(256) k_fc2(
    const float* __restrict__ A, const float* __restrict__ Wt,
    const float* __restrict__ bias, float* __restrict__ C) {
    __shared__ float As[64][FC_R];
    int t = threadIdx.x;
    int r0 = blockIdx.y * FC_R;
    int c0 = blockIdx.x * 1024 + t * 4;
    {
        int r = t >> 4, kq = (t & 15) * 4;
        float4 v = *(const float4*)(A + (size_t)(r0 + r) * 64 + kq);
        As[kq + 0][r] = v.x; As[kq + 1][r] = v.y;
        As[kq + 2][r] = v.z; As[kq + 3][r] = v.w;
    }
    __syncthreads();
    float acc[FC_R][4] = {};
    #pragma unroll 4
    for (int k = 0; k < 64; k++) {
        float4 wv = *(const float4*)(Wt + (size_t)k * WT_LD + c0);
        float4 a0 = *(const float4*)&As[k][0];
        float4 a1 = *(const float4*)&As[k][4];
        float4 a2 = *(const float4*)&As[k][8];
        float4 a3 = *(const float4*)&As[k][12];
        float ar[FC_R] = {a0.x, a0.y, a0.z, a0.w, a1.x, a1.y, a1.z, a1.w,
                          a2.x, a2.y, a2.z, a2.w, a3.x, a3.y, a3.z, a3.w};
        float wr[4] = {wv.x, wv.y, wv.z, wv.w};
        #pragma unroll
        for (int r = 0; r < FC_R; r++)
            #pragma unroll
            for (int j = 0; j < 4; j++)
                acc[r][j] = fmaf(ar[r], wr[j], acc[r][j]);
    }
    if (c0 < ODIM) {   // ODIM % 4 == 0: float4 chunk fully valid or fully out
        float4 bv = *(const float4*)(bias + c0);
        #pragma unroll
        for (int r = 0; r < FC_R; r++) {
            float4 o = make_float4(acc[r][0] + bv.x, acc[r][1] + bv.y,
                                   acc[r][2] + bv.z, acc[r][3] + bv.w);
            *(float4*)&C[(size_t)(r0 + r) * ODIM + c0] = o;
        }
    }
}

extern "C" void kernel_launch(void* const* d_in, const int* in_sizes, int n_in,
                              void* d_out, int out_size, void* d_ws, size_t ws_size,
                              hipStream_t stream) {
    const float* x     = (const float*)d_in[0];
    const int*   ei    = (const int*)d_in[1];
    const float* W1l   = (const float*)d_in[2];
    const float* b1l   = (const float*)d_in[3];
    const float* W1r   = (const float*)d_in[4];
    const float* b1r   = (const float*)d_in[5];
    const float* att1  = (const float*)d_in[6];
    const float* bias1 = (const float*)d_in[7];
    const float* W2l   = (const float*)d_in[8];
    const float* b2l   = (const float*)d_in[9];
    const float* W2r   = (const float*)d_in[10];
    const float* b2r   = (const float*)d_in[11];
    const float* att2  = (const float*)d_in[12];
    const float* bias2 = (const float*)d_in[13];
    const float* fcw   = (const float*)d_in[14];
    const float* fcb   = (const float*)d_in[15];
    float* out = (float*)d_out;

    char* p = (char*)d_ws;
    auto carve = [&](size_t bytes) {
        void* r = (void*)p;
        p += (bytes + 255) & ~(size_t)255;
        return r;
    };
    int* deg    = (int*)carve((size_t)NN * 4);
    int* rowptr = (int*)carve((size_t)(NN + 1) * 4);
    int* cursor = (int*)carve((size_t)NN * 4);
    int* csr    = (int*)carve((size_t)ET * 4);
    int* flag   = (int*)carve(256);
    float* Wt  = (float*)carve((size_t)64 * WT_LD * 4);
    float* xl1 = (float*)carve((size_t)NN * 512 * 4);
    float* xr1 = (float*)carve((size_t)NN * 512 * 4);
    float* h1  = (float*)carve((size_t)NN * 512 * 4);
    float* xl2 = xl1;                            // aliases: xl1/xr1 dead after k_gat1
    float* xr2 = xl1 + (size_t)NN * 64;
    float* h2  = xl1 + (size_t)NN * 128;

    // prep (transpose + deg init + format detect), then CSR by destination
    k_prep<<<PREPB, 256, 0, stream>>>(ei, flag, deg, fcw, Wt);
    k_hist<<<(NE + 255) / 256, 256, 0, stream>>>(ei, flag, deg);
    k_scan<<<1, 1024, 0, stream>>>(deg, rowptr, cursor);
    k_scatter<<<(ET + 255) / 256, 256, 0, stream>>>(ei, flag, cursor, csr);

    // layer 1: fused xl1/xr1 GEMM pair (8x4-per-thread LDS-economical kernel)
    dim3 g1((NN + 63) / 64, 512 / 64);
    k_gemm12_big<<<g1, 128, 0, stream>>>(x, W1l, b1l, W1r, b1r, xl1, xr1, NN, 512, 512);
    k_gat1<<<(NN * 64 + 255) / 256, 256, 0, stream>>>(xl1, xr1, att1, bias1, rowptr, csr, h1);

    // layer 2: fused xl2/xr2 GEMM pair (small-N path)
    dim3 g2((NN + 63) / 64, 1);
    k_gemm12<<<g2, 256, 0, stream>>>(h1, W2l, b2l, W2r, b2r, xl2, xr2, NN, 64, 512);
    k_gat2<<<(NN * 64 + 255) / 256, 256, 0, stream>>>(xl2, xr2, att2, bias2, rowptr, csr, h2);

    // FC head: 5 col-blocks x 625 row-blocks
    dim3 g3((ODIM + 1023) / 1024, NN / FC_R);
    k_fc2<<<g3, 256, 0, stream>>>(h2, Wt, fcb, out);
}

// Round 5
// 597.791 us; speedup vs baseline: 1.0123x; 1.0123x over previous
//
#include <hip/hip_runtime.h>

#define NN     10000
#define HEADS  8
#define HID    64
#define ODIM   5000
#define NE     160000
#define ET     170000   // NE + NN self-loops
#define NEG    0.2f
#define WT_LD  5120     // padded leading dim of transposed fc_w
#define TRB    79       // ceil(ODIM/64) transpose blocks
#define DEGB   40       // ceil(NN/256) deg-init blocks
#define PREPB  (TRB + DEGB + 1)
#define FC_R   16       // fc2 rows per block

// -------- edge_index storage-format detection (int32 vs int64 words) --------
__device__ __forceinline__ int ld_idx(const int* ei, int k, int mode) {
    return mode ? ei[2 * k] : ei[k];   // little-endian lo word carries the id
}

// prep: fc_w transpose (blocks 0..TRB-1), deg init (TRB..TRB+DEGB-1), detect (last)
__global__ void __launch_bounds__(256) k_prep(
    const int* __restrict__ ei, int* __restrict__ flag,
    int* __restrict__ deg,
    const float* __restrict__ W, float* __restrict__ Wt) {
    __shared__ float T[64][65];
    __shared__ int nz;
    int bid = blockIdx.x, t = threadIdx.x;
    if (bid < TRB) {
        int c0 = bid * 64;
        int cl = t >> 2, kq = (t & 3) * 16;
        if (c0 + cl < ODIM) {
            #pragma unroll
            for (int q = 0; q < 4; q++) {
                float4 v = *(const float4*)(W + (size_t)(c0 + cl) * 64 + kq + q * 4);
                T[cl][kq + q * 4 + 0] = v.x;
                T[cl][kq + q * 4 + 1] = v.y;
                T[cl][kq + q * 4 + 2] = v.z;
                T[cl][kq + q * 4 + 3] = v.w;
            }
        } else {
            #pragma unroll
            for (int q = 0; q < 16; q++) T[cl][kq + q] = 0.f;   // zero pad cols
        }
        __syncthreads();
        int kl = t >> 2, cq = (t & 3) * 16;
        #pragma unroll
        for (int q = 0; q < 4; q++) {
            float4 v = make_float4(T[cq + q * 4 + 0][kl], T[cq + q * 4 + 1][kl],
                                   T[cq + q * 4 + 2][kl], T[cq + q * 4 + 3][kl]);
            *(float4*)(Wt + (size_t)kl * WT_LD + c0 + cq + q * 4) = v;
        }
    } else if (bid < TRB + DEGB) {
        int i = (bid - TRB) * 256 + t;
        if (i < NN) deg[i] = 1;   // self-loop
    } else {
        if (t == 0) nz = 0;
        __syncthreads();
        int c = 0;
        #pragma unroll
        for (int q = 0; q < 4; q++)
            if (ei[2 * (t * 4 + q) + 1] != 0) c++;
        if (c) atomicAdd(&nz, c);
        __syncthreads();
        if (t == 0) *flag = (nz == 0) ? 1 : 0;
    }
}

// ---------------- CSR build (by dst) ----------------
__global__ void k_hist(const int* __restrict__ ei, const int* __restrict__ flag,
                       int* __restrict__ deg) {
    int e = blockIdx.x * blockDim.x + threadIdx.x;
    if (e < NE) atomicAdd(&deg[ld_idx(ei, NE + e, *flag)], 1);
}

// wave-shuffle scan: 10 chunks x 3 barriers
__global__ void k_scan(const int* __restrict__ deg, int* __restrict__ rowptr,
                       int* __restrict__ cursor) {
    __shared__ int wsum[16];
    __shared__ int carry;
    int t = threadIdx.x, lane = t & 63, wv = t >> 6;
    if (t == 0) carry = 0;
    __syncthreads();
    for (int base = 0; base < NN; base += 1024) {
        int i = base + t;
        int v = (i < NN) ? deg[i] : 0;
        int s = v;
        #pragma unroll
        for (int off = 1; off < 64; off <<= 1) {
            int u = __shfl_up(s, off, 64);
            if (lane >= off) s += u;
        }
        if (lane == 63) wsum[wv] = s;
        __syncthreads();
        if (t == 0) {
            int run = carry;
            #pragma unroll
            for (int j = 0; j < 16; j++) { int tmp = wsum[j]; wsum[j] = run; run += tmp; }
            carry = run;
        }
        __syncthreads();
        if (i < NN) { int ex = wsum[wv] + s - v; rowptr[i] = ex; cursor[i] = ex; }
        __syncthreads();   // protect wsum before next chunk overwrites
    }
    if (t == 0) rowptr[NN] = carry;
}

__global__ void k_scatter(const int* __restrict__ ei, const int* __restrict__ flag,
                          int* __restrict__ cursor, int* __restrict__ csr) {
    int e = blockIdx.x * blockDim.x + threadIdx.x;
    if (e < NE) {
        int mode = *flag;
        int d = ld_idx(ei, NE + e, mode);
        int pos = atomicAdd(&cursor[d], 1);
        csr[pos] = ld_idx(ei, e, mode);
    } else if (e < ET) {
        int n = e - NE;
        int pos = atomicAdd(&cursor[n], 1);
        csr[pos] = n;   // self-loop src == dst
    }
}

// ---- layer-1 pair GEMM: 128x64 tile, 256 threads (4 waves), 8x4/thread ----
// Balanced ratio: 64B LDS-read per 64 FMA per thread per k (round-4's win),
// PLUS register prefetch: loads for tile kt+32 issue before compute of kt,
// hiding the ~700cyc global latency that killed round-4 (VALUBusy 46%, occ 16%).
// Grid is (col=8, row=79): the 8 col-blocks sharing A-rows launch adjacently
// so L3 absorbs the 8x re-read of x.
#define L1_LOAD(KT)                                                          \
    do {                                                                     \
        if (rowA < NN) {                                                     \
            const float* ap_ = Aq + (KT);                                    \
            a4[0] = *(const float4*)(ap_);                                   \
            a4[1] = *(const float4*)(ap_ + 4);                               \
            a4[2] = *(const float4*)(ap_ + 8);                               \
            a4[3] = *(const float4*)(ap_ + 12);                              \
        }                                                                    \
        const float* lp_ = Lq + (KT);                                        \
        l4[0] = *(const float4*)(lp_);  l4[1] = *(const float4*)(lp_ + 4);   \
        const float* rp_ = Rq + (KT);                                        \
        r4[0] = *(const float4*)(rp_);  r4[1] = *(const float4*)(rp_ + 4);   \
    } while (0)

__global__ void __launch_bounds__(256) k_gemm1(
    const float* __restrict__ A,
    const float* __restrict__ Wl, const float* __restrict__ bl,
    const float* __restrict__ Wr, const float* __restrict__ br,
    float* __restrict__ Cl, float* __restrict__ Cr) {
    __shared__ float As[32][128];
    __shared__ float Ls[32][64];
    __shared__ float Rs[32][64];
    const int t = threadIdx.x;
    const int n0 = blockIdx.x * 64;      // col-block (8)
    const int m0 = blockIdx.y * 128;     // row-block (79)
    const int tx = t & 15, ty = t >> 4;  // tx: 4-col group, ty: 8-row group
    const int arow = t >> 1, akc = (t & 1) * 16;   // A stage: 16 floats/thread
    const int wrow = t & 63, wkc = (t >> 6) * 8;   // W stage: 8 floats/thread
    const int rowA = m0 + arow;
    const float* Aq = A  + (size_t)rowA * 512 + akc;
    const float* Lq = Wl + (size_t)(n0 + wrow) * 512 + wkc;
    const float* Rq = Wr + (size_t)(n0 + wrow) * 512 + wkc;
    float4 a4[4], l4[2], r4[2];
    a4[0] = a4[1] = a4[2] = a4[3] = make_float4(0.f, 0.f, 0.f, 0.f);
    float accL[8][4] = {}, accR[8][4] = {};

    L1_LOAD(0);
    for (int kt = 0; kt < 512; kt += 32) {
        __syncthreads();   // all waves done reading LDS from previous tile
        #pragma unroll
        for (int q = 0; q < 4; q++) {      // A writes: 2 lanes/bank (free)
            int k = akc + q * 4;
            As[k + 0][arow] = a4[q].x; As[k + 1][arow] = a4[q].y;
            As[k + 2][arow] = a4[q].z; As[k + 3][arow] = a4[q].w;
        }
        #pragma unroll
        for (int q = 0; q < 2; q++) {      // W writes: 2 lanes/bank (free)
            int k = wkc + q * 4;
            Ls[k + 0][wrow] = l4[q].x; Ls[k + 1][wrow] = l4[q].y;
            Ls[k + 2][wrow] = l4[q].z; Ls[k + 3][wrow] = l4[q].w;
            Rs[k + 0][wrow] = r4[q].x; Rs[k + 1][wrow] = r4[q].y;
            Rs[k + 2][wrow] = r4[q].z; Rs[k + 3][wrow] = r4[q].w;
        }
        __syncthreads();
        if (kt < 480) { L1_LOAD(kt + 32); }   // prefetch next tile: latency
                                              // hides under the compute below
        #pragma unroll
        for (int k = 0; k < 32; k++) {
            float4 x0 = *(const float4*)&As[k][ty * 8];      // broadcast
            float4 x1 = *(const float4*)&As[k][ty * 8 + 4];
            float4 lv = *(const float4*)&Ls[k][tx * 4];      // 2-way (free)
            float4 rv = *(const float4*)&Rs[k][tx * 4];
            float ar[8] = {x0.x, x0.y, x0.z, x0.w, x1.x, x1.y, x1.z, x1.w};
            float lb[4] = {lv.x, lv.y, lv.z, lv.w};
            float rb[4] = {rv.x, rv.y, rv.z, rv.w};
            #pragma unroll
            for (int i = 0; i < 8; i++)
                #pragma unroll
                for (int j = 0; j < 4; j++) {
                    accL[i][j] = fmaf(ar[i], lb[j], accL[i][j]);
                    accR[i][j] = fmaf(ar[i], rb[j], accR[i][j]);
                }
        }
    }
    int col0 = n0 + tx * 4;
    float4 bvl = *(const float4*)&bl[col0];
    float4 bvr = *(const float4*)&br[col0];
    #pragma unroll
    for (int i = 0; i < 8; i++) {
        int rr = m0 + ty * 8 + i;
        if (rr < NN) {
            float4 ol = make_float4(accL[i][0] + bvl.x, accL[i][1] + bvl.y,
                                    accL[i][2] + bvl.z, accL[i][3] + bvl.w);
            float4 orr = make_float4(accR[i][0] + bvr.x, accR[i][1] + bvr.y,
                                     accR[i][2] + bvr.z, accR[i][3] + bvr.w);
            *(float4*)&Cl[(size_t)rr * 512 + col0] = ol;
            *(float4*)&Cr[(size_t)rr * 512 + col0] = orr;
        }
    }
}

// ---- layer-2 pair GEMM (N=64, small): 64x64 tile, 256 thr, 4x4/thread ----
__global__ void __launch_bounds__(256) k_gemm12(
    const float* __restrict__ A,
    const float* __restrict__ Wl, const float* __restrict__ bl,
    const float* __restrict__ Wr, const float* __restrict__ br,
    float* __restrict__ Cl, float* __restrict__ Cr,
    int M, int Ndim, int K) {
    __shared__ float As[32][64];
    __shared__ float Ls[32][64];
    __shared__ float Rs[32][64];
    int t = threadIdx.x;
    int m0 = blockIdx.x * 64, n0 = blockIdx.y * 64;
    int lm = t >> 2;
    int kc = (t & 3) * 8;
    int tx = t & 15, ty = t >> 4;
    int rowA = m0 + lm;
    int rowW = n0 + lm;
    float accL[4][4] = {}, accR[4][4] = {};
    for (int kt = 0; kt < K; kt += 32) {
        float av[8];
        if (rowA < M) {
            const float* ap = A + (size_t)rowA * K + kt + kc;
            float4 p0 = *(const float4*)ap;
            float4 p1 = *(const float4*)(ap + 4);
            av[0] = p0.x; av[1] = p0.y; av[2] = p0.z; av[3] = p0.w;
            av[4] = p1.x; av[5] = p1.y; av[6] = p1.z; av[7] = p1.w;
        } else {
            #pragma unroll
            for (int j = 0; j < 8; j++) av[j] = 0.f;
        }
        const float* lp = Wl + (size_t)rowW * K + kt + kc;
        float4 l0 = *(const float4*)lp;
        float4 l1 = *(const float4*)(lp + 4);
        float lv[8] = {l0.x, l0.y, l0.z, l0.w, l1.x, l1.y, l1.z, l1.w};
        const float* rp = Wr + (size_t)rowW * K + kt + kc;
        float4 r0 = *(const float4*)rp;
        float4 r1 = *(const float4*)(rp + 4);
        float rv[8] = {r0.x, r0.y, r0.z, r0.w, r1.x, r1.y, r1.z, r1.w};
        #pragma unroll
        for (int j = 0; j < 8; j++) As[kc + j][lm] = av[j];
        #pragma unroll
        for (int j = 0; j < 8; j++) Ls[kc + j][lm] = lv[j];
        #pragma unroll
        for (int j = 0; j < 8; j++) Rs[kc + j][lm] = rv[j];
        __syncthreads();
        #pragma unroll
        for (int k = 0; k < 32; k++) {
            float4 a4 = *(const float4*)&As[k][ty * 4];
            float4 b4 = *(const float4*)&Ls[k][tx * 4];
            float4 c4 = *(const float4*)&Rs[k][tx * 4];
            float aa[4] = {a4.x, a4.y, a4.z, a4.w};
            float bb[4] = {b4.x, b4.y, b4.z, b4.w};
            float cc[4] = {c4.x, c4.y, c4.z, c4.w};
            #pragma unroll
            for (int i = 0; i < 4; i++)
                #pragma unroll
                for (int j = 0; j < 4; j++) {
                    accL[i][j] = fmaf(aa[i], bb[j], accL[i][j]);
                    accR[i][j] = fmaf(aa[i], cc[j], accR[i][j]);
                }
        }
        __syncthreads();
    }
    int col0 = n0 + tx * 4;
    float4 bvl = *(const float4*)&bl[col0];
    float4 bvr = *(const float4*)&br[col0];
    #pragma unroll
    for (int i = 0; i < 4; i++) {
        int r = m0 + ty * 4 + i;
        if (r < M) {
            float4 ol = make_float4(accL[i][0] + bvl.x, accL[i][1] + bvl.y,
                                    accL[i][2] + bvl.z, accL[i][3] + bvl.w);
            float4 orr = make_float4(accR[i][0] + bvr.x, accR[i][1] + bvr.y,
                                     accR[i][2] + bvr.z, accR[i][3] + bvr.w);
            *(float4*)&Cl[(size_t)r * Ndim + col0] = ol;
            *(float4*)&Cr[(size_t)r * Ndim + col0] = orr;
        }
    }
}

// ------- fused GATv2 layer 1: one wave per node, online softmax -------
__global__ void __launch_bounds__(256) k_gat1(
    const float* __restrict__ xl, const float* __restrict__ xr,
    const float* __restrict__ att, const float* __restrict__ bias,
    const int* __restrict__ rowptr, const int* __restrict__ csr,
    float* __restrict__ out) {
    int wid = (blockIdx.x * blockDim.x + threadIdx.x) >> 6;
    int lane = threadIdx.x & 63;
    if (wid >= NN) return;
    int n = wid;
    int off = lane * 4;            // = (l>>4)*64 + 4*(l&15)
    const float4* xr4  = (const float4*)(xr + (size_t)n * 512 + off);
    const float4* att4 = (const float4*)(att + off);
    float4 xrA = xr4[0],  xrB = xr4[64];    // +256 floats
    float4 atA = att4[0], atB = att4[64];
    float4 accA = make_float4(0.f, 0.f, 0.f, 0.f);
    float4 accB = make_float4(0.f, 0.f, 0.f, 0.f);
    float lA = 0.f, lB = 0.f, mA = -1e30f, mB = -1e30f;

    int p0 = rowptr[n], p1 = rowptr[n + 1];
    int deg = p1 - p0;             // >= 1 (self-loop)
    float4 a0, b0, a1, b1;
    {
        const float4* p = (const float4*)(xl + (size_t)csr[p0] * 512 + off);
        a0 = p[0]; b0 = p[64];
    }
    if (deg > 1) {
        const float4* p = (const float4*)(xl + (size_t)csr[p0 + 1] * 512 + off);
        a1 = p[0]; b1 = p[64];
    } else { a1 = a0; b1 = b0; }
    for (int i = 0; i < deg; i++) {
        float4 cxa = a0, cxb = b0;
        a0 = a1; b0 = b1;
        if (i + 2 < deg) {
            const float4* np = (const float4*)(xl + (size_t)csr[p0 + i + 2] * 512 + off);
            a1 = np[0]; b1 = np[64];
        }
        // leaky(x+xr) . att, 4-channel partials
        float vA0 = cxa.x + xrA.x, vA1 = cxa.y + xrA.y,
              vA2 = cxa.z + xrA.z, vA3 = cxa.w + xrA.w;
        float vB0 = cxb.x + xrB.x, vB1 = cxb.y + xrB.y,
              vB2 = cxb.z + xrB.z, vB3 = cxb.w + xrB.w;
        vA0 = (vA0 > 0.f) ? vA0 : NEG * vA0;  vA1 = (vA1 > 0.f) ? vA1 : NEG * vA1;
        vA2 = (vA2 > 0.f) ? vA2 : NEG * vA2;  vA3 = (vA3 > 0.f) ? vA3 : NEG * vA3;
        vB0 = (vB0 > 0.f) ? vB0 : NEG * vB0;  vB1 = (vB1 > 0.f) ? vB1 : NEG * vB1;
        vB2 = (vB2 > 0.f) ? vB2 : NEG * vB2;  vB3 = (vB3 > 0.f) ? vB3 : NEG * vB3;
        float sA = vA0 * atA.x + vA1 * atA.y + vA2 * atA.z + vA3 * atA.w;
        float sB = vB0 * atB.x + vB1 * atB.y + vB2 * atB.z + vB3 * atB.w;
        #pragma unroll
        for (int m = 1; m <= 8; m <<= 1) {
            sA += __shfl_xor(sA, m, 64);
            sB += __shfl_xor(sB, m, 64);
        }
        // online softmax update, head A
        float mnA = fmaxf(mA, sA);
        float scA = __expf(mA - mnA), peA = __expf(sA - mnA);
        accA.x = accA.x * scA + peA * cxa.x;  accA.y = accA.y * scA + peA * cxa.y;
        accA.z = accA.z * scA + peA * cxa.z;  accA.w = accA.w * scA + peA * cxa.w;
        lA = lA * scA + peA;  mA = mnA;
        // head B
        float mnB = fmaxf(mB, sB);
        float scB = __expf(mB - mnB), peB = __expf(sB - mnB);
        accB.x = accB.x * scB + peB * cxb.x;  accB.y = accB.y * scB + peB * cxb.y;
        accB.z = accB.z * scB + peB * cxb.z;  accB.w = accB.w * scB + peB * cxb.w;
        lB = lB * scB + peB;  mB = mnB;
    }
    float rA = 1.f / (lA + 1e-16f), rB = 1.f / (lB + 1e-16f);
    float4 biA = *(const float4*)(bias + off);
    float4 biB = *(const float4*)(bias + off + 256);
    float4 oA = make_float4(fmaxf(accA.x * rA + biA.x, 0.f),
                            fmaxf(accA.y * rA + biA.y, 0.f),
                            fmaxf(accA.z * rA + biA.z, 0.f),
                            fmaxf(accA.w * rA + biA.w, 0.f));
    float4 oB = make_float4(fmaxf(accB.x * rB + biB.x, 0.f),
                            fmaxf(accB.y * rB + biB.y, 0.f),
                            fmaxf(accB.z * rB + biB.z, 0.f),
                            fmaxf(accB.w * rB + biB.w, 0.f));
    float4* op = (float4*)(out + (size_t)n * 512 + off);
    op[0]  = oA;      // ReLU applied (layer-1 activation)
    op[64] = oB;
}

// ------- fused GATv2 layer 2 (1 head, 64 ch): one wave per node -------
__global__ void __launch_bounds__(256) k_gat2(
    const float* __restrict__ xl, const float* __restrict__ xr,
    const float* __restrict__ att, const float* __restrict__ bias,
    const int* __restrict__ rowptr, const int* __restrict__ csr,
    float* __restrict__ out) {
    int wid = (blockIdx.x * blockDim.x + threadIdx.x) >> 6;
    int lane = threadIdx.x & 63;
    if (wid >= NN) return;
    int n = wid;
    float xrv = xr[(size_t)n * 64 + lane];
    float atv = att[lane];
    float acc = 0.f, lsum = 0.f, mmax = -1e30f;
    int p0 = rowptr[n], p1 = rowptr[n + 1];
    int deg = p1 - p0;
    float x0 = xl[(size_t)csr[p0] * 64 + lane];
    float x1 = (deg > 1) ? xl[(size_t)csr[p0 + 1] * 64 + lane] : x0;
    for (int i = 0; i < deg; i++) {
        float xs = x0;
        x0 = x1;
        if (i + 2 < deg) x1 = xl[(size_t)csr[p0 + i + 2] * 64 + lane];
        float v = xs + xrv;
        v = (v > 0.f) ? v : NEG * v;
        float sc = v * atv;
        #pragma unroll
        for (int off = 32; off > 0; off >>= 1)
            sc += __shfl_xor(sc, off, 64);
        float mn = fmaxf(mmax, sc);
        float scale = __expf(mmax - mn);
        float pe = __expf(sc - mn);
        acc = acc * scale + pe * xs;
        lsum = lsum * scale + pe;
        mmax = mn;
    }
    float o = acc / (lsum + 1e-16f) + bias[lane];
    out[(size_t)n * 64 + lane] = (o > 0.f) ? o : 0.f;   // ReLU after layer 2
}

// --- FC: out[10000,5000] = h2[10000,64] @ Wt + fc_b ---
__global__ void __launch_bounds__(256) k_fc2(
    const float* __restrict__ A, const float* __restrict__ Wt,
    const float* __restrict__ bias, float* __restrict__ C) {
    __shared__ float As[64][FC_R];
    int t = threadIdx.x;
    int r0 = blockIdx.y * FC_R;
    int c0 = blockIdx.x * 1024 + t * 4;
    {
        int r = t >> 4, kq = (t & 15) * 4;
        float4 v = *(const float4*)(A + (size_t)(r0 + r) * 64 + kq);
        As[kq + 0][r] = v.x; As[kq + 1][r] = v.y;
        As[kq + 2][r] = v.z; As[kq + 3][r] = v.w;
    }
    __syncthreads();
    float acc[FC_R][4] = {};
    #pragma unroll 4
    for (int k = 0; k < 64; k++) {
        float4 wv = *(const float4*)(Wt + (size_t)k * WT_LD + c0);
        float4 a0 = *(const float4*)&As[k][0];
        float4 a1 = *(const float4*)&As[k][4];
        float4 a2 = *(const float4*)&As[k][8];
        float4 a3 = *(const float4*)&As[k][12];
        float ar[FC_R] = {a0.x, a0.y, a0.z, a0.w, a1.x, a1.y, a1.z, a1.w,
                          a2.x, a2.y, a2.z, a2.w, a3.x, a3.y, a3.z, a3.w};
        float wr[4] = {wv.x, wv.y, wv.z, wv.w};
        #pragma unroll
        for (int r = 0; r < FC_R; r++)
            #pragma unroll
            for (int j = 0; j < 4; j++)
                acc[r][j] = fmaf(ar[r], wr[j], acc[r][j]);
    }
    if (c0 < ODIM) {   // ODIM % 4 == 0: float4 chunk fully valid or fully out
        float4 bv = *(const float4*)(bias + c0);
        #pragma unroll
        for (int r = 0; r < FC_R; r++) {
            float4 o = make_float4(acc[r][0] + bv.x, acc[r][1] + bv.y,
                                   acc[r][2] + bv.z, acc[r][3] + bv.w);
            *(float4*)&C[(size_t)(r0 + r) * ODIM + c0] = o;
        }
    }
}

extern "C" void kernel_launch(void* const* d_in, const int* in_sizes, int n_in,
                              void* d_out, int out_size, void* d_ws, size_t ws_size,
                              hipStream_t stream) {
    const float* x     = (const float*)d_in[0];
    const int*   ei    = (const int*)d_in[1];
    const float* W1l   = (const float*)d_in[2];
    const float* b1l   = (const float*)d_in[3];
    const float* W1r   = (const float*)d_in[4];
    const float* b1r   = (const float*)d_in[5];
    const float* att1  = (const float*)d_in[6];
    const float* bias1 = (const float*)d_in[7];
    const float* W2l   = (const float*)d_in[8];
    const float* b2l   = (const float*)d_in[9];
    const float* W2r   = (const float*)d_in[10];
    const float* b2r   = (const float*)d_in[11];
    const float* att2  = (const float*)d_in[12];
    const float* bias2 = (const float*)d_in[13];
    const float* fcw   = (const float*)d_in[14];
    const float* fcb   = (const float*)d_in[15];
    float* out = (float*)d_out;

    char* p = (char*)d_ws;
    auto carve = [&](size_t bytes) {
        void* r = (void*)p;
        p += (bytes + 255) & ~(size_t)255;
        return r;
    };
    int* deg    = (int*)carve((size_t)NN * 4);
    int* rowptr = (int*)carve((size_t)(NN + 1) * 4);
    int* cursor = (int*)carve((size_t)NN * 4);
    int* csr    = (int*)carve((size_t)ET * 4);
    int* flag   = (int*)carve(256);
    float* Wt  = (float*)carve((size_t)64 * WT_LD * 4);
    float* xl1 = (float*)carve((size_t)NN * 512 * 4);
    float* xr1 = (float*)carve((size_t)NN * 512 * 4);
    float* h1  = (float*)carve((size_t)NN * 512 * 4);
    float* xl2 = xl1;                            // aliases: xl1/xr1 dead after k_gat1
    float* xr2 = xl1 + (size_t)NN * 64;
    float* h2  = xl1 + (size_t)NN * 128;

    // prep (transpose + deg init + format detect), then CSR by destination
    k_prep<<<PREPB, 256, 0, stream>>>(ei, flag, deg, fcw, Wt);
    k_hist<<<(NE + 255) / 256, 256, 0, stream>>>(ei, flag, deg);
    k_scan<<<1, 1024, 0, stream>>>(deg, rowptr, cursor);
    k_scatter<<<(ET + 255) / 256, 256, 0, stream>>>(ei, flag, cursor, csr);

    // layer 1: fused xl1/xr1 GEMM pair (128x64 tile, prefetched)
    dim3 g1(8, (NN + 127) / 128);   // x = col-block, y = row-block
    k_gemm1<<<g1, 256, 0, stream>>>(x, W1l, b1l, W1r, b1r, xl1, xr1);
    k_gat1<<<(NN * 64 + 255) / 256, 256, 0, stream>>>(xl1, xr1, att1, bias1, rowptr, csr, h1);

    // layer 2: fused xl2/xr2 GEMM pair (small-N path)
    dim3 g2((NN + 63) / 64, 1);
    k_gemm12<<<g2, 256, 0, stream>>>(h1, W2l, b2l, W2r, b2r, xl2, xr2, NN, 64, 512);
    k_gat2<<<(NN * 64 + 255) / 256, 256, 0, stream>>>(xl2, xr2, att2, bias2, rowptr, csr, h2);

    // FC head: 5 col-blocks x 625 row-blocks
    dim3 g3((ODIM + 1023) / 1024, NN / FC_R);
    k_fc2<<<g3, 256, 0, stream>>>(h2, Wt, fcb, out);
}

// Round 6
// 538.980 us; speedup vs baseline: 1.1228x; 1.1091x over previous
//
#include <hip/hip_runtime.h>

#define NN     10000
#define HEADS  8
#define HID    64
#define ODIM   5000
#define NE     160000
#define ET     170000   // NE + NN self-loops
#define NEG    0.2f
#define WT_LD  5120     // padded leading dim of transposed fc_w
#define TRB    79       // ceil(ODIM/64) transpose blocks
#define DEGB   40       // ceil(NN/256) deg-init blocks
#define PREPB  (TRB + DEGB + 1)
#define FC_R   16       // fc2 rows per block

typedef _Float16 f16x8 __attribute__((ext_vector_type(8)));
typedef float f32x4 __attribute__((ext_vector_type(4)));

// -------- edge_index storage-format detection (int32 vs int64 words) --------
__device__ __forceinline__ int ld_idx(const int* ei, int k, int mode) {
    return mode ? ei[2 * k] : ei[k];   // little-endian lo word carries the id
}

// prep: fc_w transpose (blocks 0..TRB-1), deg init (TRB..TRB+DEGB-1), detect (last)
__global__ void __launch_bounds__(256) k_prep(
    const int* __restrict__ ei, int* __restrict__ flag,
    int* __restrict__ deg,
    const float* __restrict__ W, float* __restrict__ Wt) {
    __shared__ float T[64][65];
    __shared__ int nz;
    int bid = blockIdx.x, t = threadIdx.x;
    if (bid < TRB) {
        int c0 = bid * 64;
        int cl = t >> 2, kq = (t & 3) * 16;
        if (c0 + cl < ODIM) {
            #pragma unroll
            for (int q = 0; q < 4; q++) {
                float4 v = *(const float4*)(W + (size_t)(c0 + cl) * 64 + kq + q * 4);
                T[cl][kq + q * 4 + 0] = v.x;
                T[cl][kq + q * 4 + 1] = v.y;
                T[cl][kq + q * 4 + 2] = v.z;
                T[cl][kq + q * 4 + 3] = v.w;
            }
        } else {
            #pragma unroll
            for (int q = 0; q < 16; q++) T[cl][kq + q] = 0.f;   // zero pad cols
        }
        __syncthreads();
        int kl = t >> 2, cq = (t & 3) * 16;
        #pragma unroll
        for (int q = 0; q < 4; q++) {
            float4 v = make_float4(T[cq + q * 4 + 0][kl], T[cq + q * 4 + 1][kl],
                                   T[cq + q * 4 + 2][kl], T[cq + q * 4 + 3][kl]);
            *(float4*)(Wt + (size_t)kl * WT_LD + c0 + cq + q * 4) = v;
        }
    } else if (bid < TRB + DEGB) {
        int i = (bid - TRB) * 256 + t;
        if (i < NN) deg[i] = 1;   // self-loop
    } else {
        if (t == 0) nz = 0;
        __syncthreads();
        int c = 0;
        #pragma unroll
        for (int q = 0; q < 4; q++)
            if (ei[2 * (t * 4 + q) + 1] != 0) c++;
        if (c) atomicAdd(&nz, c);
        __syncthreads();
        if (t == 0) *flag = (nz == 0) ? 1 : 0;
    }
}

// ---------------- CSR build (by dst) ----------------
__global__ void k_hist(const int* __restrict__ ei, const int* __restrict__ flag,
                       int* __restrict__ deg) {
    int e = blockIdx.x * blockDim.x + threadIdx.x;
    if (e < NE) atomicAdd(&deg[ld_idx(ei, NE + e, *flag)], 1);
}

// wave-shuffle scan: 10 chunks x 3 barriers
__global__ void k_scan(const int* __restrict__ deg, int* __restrict__ rowptr,
                       int* __restrict__ cursor) {
    __shared__ int wsum[16];
    __shared__ int carry;
    int t = threadIdx.x, lane = t & 63, wv = t >> 6;
    if (t == 0) carry = 0;
    __syncthreads();
    for (int base = 0; base < NN; base += 1024) {
        int i = base + t;
        int v = (i < NN) ? deg[i] : 0;
        int s = v;
        #pragma unroll
        for (int off = 1; off < 64; off <<= 1) {
            int u = __shfl_up(s, off, 64);
            if (lane >= off) s += u;
        }
        if (lane == 63) wsum[wv] = s;
        __syncthreads();
        if (t == 0) {
            int run = carry;
            #pragma unroll
            for (int j = 0; j < 16; j++) { int tmp = wsum[j]; wsum[j] = run; run += tmp; }
            carry = run;
        }
        __syncthreads();
        if (i < NN) { int ex = wsum[wv] + s - v; rowptr[i] = ex; cursor[i] = ex; }
        __syncthreads();   // protect wsum before next chunk overwrites
    }
    if (t == 0) rowptr[NN] = carry;
}

__global__ void k_scatter(const int* __restrict__ ei, const int* __restrict__ flag,
                          int* __restrict__ cursor, int* __restrict__ csr) {
    int e = blockIdx.x * blockDim.x + threadIdx.x;
    if (e < NE) {
        int mode = *flag;
        int d = ld_idx(ei, NE + e, mode);
        int pos = atomicAdd(&cursor[d], 1);
        csr[pos] = ld_idx(ei, e, mode);
    } else if (e < ET) {
        int n = e - NE;
        int pos = atomicAdd(&cursor[n], 1);
        csr[pos] = n;   // self-loop src == dst
    }
}

// -------- fp32 -> (hi fp16, lo fp16) split: x = hi + lo + O(2^-22 x) --------
__device__ __forceinline__ void split_f16(float x, _Float16& h, _Float16& l) {
    _Float16 hh = (_Float16)x;
    l = (_Float16)(x - (float)hh);
    h = hh;
}
__device__ __forceinline__ unsigned int pk2(_Float16 a, _Float16 b) {
    return (unsigned int)__builtin_bit_cast(unsigned short, a) |
           ((unsigned int)__builtin_bit_cast(unsigned short, b) << 16);
}

// split up to 3 segments in one launch; unit = 8 floats
__global__ void __launch_bounds__(256) k_split3(
    const float* __restrict__ s0, _Float16* __restrict__ d0h, _Float16* __restrict__ d0l, int n0,
    const float* __restrict__ s1, _Float16* __restrict__ d1h, _Float16* __restrict__ d1l, int n1,
    const float* __restrict__ s2, _Float16* __restrict__ d2h, _Float16* __restrict__ d2l, int n2) {
    int i = blockIdx.x * 256 + threadIdx.x;
    int e1 = n0 + n1, e2 = e1 + n2;
    if (i >= e2) return;
    const float* s; _Float16* ph; _Float16* pl;
    if (i >= e1)      { i -= e1; s = s2; ph = d2h; pl = d2l; }
    else if (i >= n0) { i -= n0; s = s1; ph = d1h; pl = d1l; }
    else              {          s = s0; ph = d0h; pl = d0l; }
    float4 x0 = *(const float4*)(s + (size_t)i * 8);
    float4 x1 = *(const float4*)(s + (size_t)i * 8 + 4);
    _Float16 h0, h1, h2, h3, h4, h5, h6, h7, l0, l1, l2, l3, l4, l5, l6, l7;
    split_f16(x0.x, h0, l0); split_f16(x0.y, h1, l1);
    split_f16(x0.z, h2, l2); split_f16(x0.w, h3, l3);
    split_f16(x1.x, h4, l4); split_f16(x1.y, h5, l5);
    split_f16(x1.z, h6, l6); split_f16(x1.w, h7, l7);
    *(uint4*)(ph + (size_t)i * 8) = make_uint4(pk2(h0,h1), pk2(h2,h3), pk2(h4,h5), pk2(h6,h7));
    *(uint4*)(pl + (size_t)i * 8) = make_uint4(pk2(l0,l1), pk2(l2,l3), pk2(l4,l5), pk2(l6,l7));
}

// ---- MFMA pair GEMM (fp16 2-split, 3 passes): C{0,1} = A @ W{0,1}^T + b ----
// Block: 256 thr / 4 waves, output 128 rows x 64 cols x BOTH matrices.
// K staged in BK=64 slabs; LDS layout [kg][row][8] so every frag read and
// stage write is a contiguous conflict-free 16B chunk.
// Frags (m89-verified 16x16x32): a: lane l holds A[row=l&15][k=(l>>4)*8+j];
// b: W[col-row=l&15][same k]; D: row=(l>>4)*4+r, col=l&15. Any HW k-perm
// cancels because a and b use identical k-addressing.
__global__ void __launch_bounds__(256) k_gemm_mfma(
    const _Float16* __restrict__ Ah, const _Float16* __restrict__ Al,
    const _Float16* __restrict__ W0h, const _Float16* __restrict__ W0l,
    const _Float16* __restrict__ W1h, const _Float16* __restrict__ W1l,
    const float* __restrict__ b0, const float* __restrict__ b1,
    float* __restrict__ C0, float* __restrict__ C1,
    int M, int nbpm) {
    __shared__ __align__(16) _Float16 sAh[8][128][8];
    __shared__ __align__(16) _Float16 sAl[8][128][8];
    __shared__ __align__(16) _Float16 sWh[2][8][64][8];
    __shared__ __align__(16) _Float16 sWl[2][8][64][8];
    const int t = threadIdx.x;
    const int w = t >> 6, lane = t & 63;
    const int lr = lane & 15, lk = lane >> 4;
    const int wm = w >> 1, wn = w & 1;
    const int n0 = blockIdx.x * 64;      // col-offset within each matrix
    const int m0 = blockIdx.y * 128;
    const int Ndim = nbpm * 64;
    f32x4 acc[2][4][2] = {};
    for (int kt = 0; kt < 512; kt += 64) {
        __syncthreads();   // prior compute finished reading LDS
        #pragma unroll
        for (int j = 0; j < 4; j++) {    // A tile: 1024 chunks x (hi,lo)
            int c = j * 256 + t;
            int row = c & 127, kg = c >> 7;
            int sr = m0 + row; sr = sr < M ? sr : M - 1;   // clamp tail rows
            const size_t go = (size_t)sr * 512 + kt + kg * 8;
            uint4 vh = *(const uint4*)(Ah + go);
            uint4 vl = *(const uint4*)(Al + go);
            *(uint4*)&sAh[kg][row][0] = vh;
            *(uint4*)&sAl[kg][row][0] = vl;
        }
        #pragma unroll
        for (int j = 0; j < 2; j++) {    // W tiles: both matrices, hi+lo
            int c = j * 256 + t;
            int wr = c & 63, kg = c >> 6;
            const size_t go = (size_t)(n0 + wr) * 512 + kt + kg * 8;
            uint4 a0 = *(const uint4*)(W0h + go);
            uint4 a1 = *(const uint4*)(W0l + go);
            uint4 a2 = *(const uint4*)(W1h + go);
            uint4 a3 = *(const uint4*)(W1l + go);
            *(uint4*)&sWh[0][kg][wr][0] = a0;
            *(uint4*)&sWl[0][kg][wr][0] = a1;
            *(uint4*)&sWh[1][kg][wr][0] = a2;
            *(uint4*)&sWl[1][kg][wr][0] = a3;
        }
        __syncthreads();
        #pragma unroll
        for (int ks = 0; ks < 2; ks++) {
            int kg = ks * 4 + lk;
            f16x8 ah[4], al[4];
            #pragma unroll
            for (int mi = 0; mi < 4; mi++) {
                int row = wm * 64 + mi * 16 + lr;
                ah[mi] = *(const f16x8*)&sAh[kg][row][0];
                al[mi] = *(const f16x8*)&sAl[kg][row][0];
            }
            #pragma unroll
            for (int mat = 0; mat < 2; mat++) {
                #pragma unroll
                for (int ni = 0; ni < 2; ni++) {
                    int wr = wn * 32 + ni * 16 + lr;
                    f16x8 bh = *(const f16x8*)&sWh[mat][kg][wr][0];
                    f16x8 bl = *(const f16x8*)&sWl[mat][kg][wr][0];
                    #pragma unroll
                    for (int mi = 0; mi < 4; mi++) {
                        acc[mat][mi][ni] = __builtin_amdgcn_mfma_f32_16x16x32_f16(ah[mi], bh, acc[mat][mi][ni], 0, 0, 0);
                        acc[mat][mi][ni] = __builtin_amdgcn_mfma_f32_16x16x32_f16(ah[mi], bl, acc[mat][mi][ni], 0, 0, 0);
                        acc[mat][mi][ni] = __builtin_amdgcn_mfma_f32_16x16x32_f16(al[mi], bh, acc[mat][mi][ni], 0, 0, 0);
                    }
                }
            }
        }
    }
    #pragma unroll
    for (int mat = 0; mat < 2; mat++) {
        float* C = mat ? C1 : C0;
        const float* bb = mat ? b1 : b0;
        #pragma unroll
        for (int ni = 0; ni < 2; ni++) {
            int col = n0 + wn * 32 + ni * 16 + lr;
            float bv = bb[col];
            #pragma unroll
            for (int mi = 0; mi < 4; mi++) {
                #pragma unroll
                for (int r = 0; r < 4; r++) {
                    int row = m0 + wm * 64 + mi * 16 + lk * 4 + r;
                    if (row < M)
                        C[(size_t)row * Ndim + col] = acc[mat][mi][ni][r] + bv;
                }
            }
        }
    }
}

// ------- fused GATv2 layer 1: one wave per node, online softmax -------
__global__ void __launch_bounds__(256) k_gat1(
    const float* __restrict__ xl, const float* __restrict__ xr,
    const float* __restrict__ att, const float* __restrict__ bias,
    const int* __restrict__ rowptr, const int* __restrict__ csr,
    float* __restrict__ out) {
    int wid = (blockIdx.x * blockDim.x + threadIdx.x) >> 6;
    int lane = threadIdx.x & 63;
    if (wid >= NN) return;
    int n = wid;
    int off = lane * 4;            // = (l>>4)*64 + 4*(l&15)
    const float4* xr4  = (const float4*)(xr + (size_t)n * 512 + off);
    const float4* att4 = (const float4*)(att + off);
    float4 xrA = xr4[0],  xrB = xr4[64];    // +256 floats
    float4 atA = att4[0], atB = att4[64];
    float4 accA = make_float4(0.f, 0.f, 0.f, 0.f);
    float4 accB = make_float4(0.f, 0.f, 0.f, 0.f);
    float lA = 0.f, lB = 0.f, mA = -1e30f, mB = -1e30f;

    int p0 = rowptr[n], p1 = rowptr[n + 1];
    int deg = p1 - p0;             // >= 1 (self-loop)
    float4 a0, b0, a1, b1;
    {
        const float4* p = (const float4*)(xl + (size_t)csr[p0] * 512 + off);
        a0 = p[0]; b0 = p[64];
    }
    if (deg > 1) {
        const float4* p = (const float4*)(xl + (size_t)csr[p0 + 1] * 512 + off);
        a1 = p[0]; b1 = p[64];
    } else { a1 = a0; b1 = b0; }
    for (int i = 0; i < deg; i++) {
        float4 cxa = a0, cxb = b0;
        a0 = a1; b0 = b1;
        if (i + 2 < deg) {
            const float4* np = (const float4*)(xl + (size_t)csr[p0 + i + 2] * 512 + off);
            a1 = np[0]; b1 = np[64];
        }
        // leaky(x+xr) . att, 4-channel partials
        float vA0 = cxa.x + xrA.x, vA1 = cxa.y + xrA.y,
              vA2 = cxa.z + xrA.z, vA3 = cxa.w + xrA.w;
        float vB0 = cxb.x + xrB.x, vB1 = cxb.y + xrB.y,
              vB2 = cxb.z + xrB.z, vB3 = cxb.w + xrB.w;
        vA0 = (vA0 > 0.f) ? vA0 : NEG * vA0;  vA1 = (vA1 > 0.f) ? vA1 : NEG * vA1;
        vA2 = (vA2 > 0.f) ? vA2 : NEG * vA2;  vA3 = (vA3 > 0.f) ? vA3 : NEG * vA3;
        vB0 = (vB0 > 0.f) ? vB0 : NEG * vB0;  vB1 = (vB1 > 0.f) ? vB1 : NEG * vB1;
        vB2 = (vB2 > 0.f) ? vB2 : NEG * vB2;  vB3 = (vB3 > 0.f) ? vB3 : NEG * vB3;
        float sA = vA0 * atA.x + vA1 * atA.y + vA2 * atA.z + vA3 * atA.w;
        float sB = vB0 * atB.x + vB1 * atB.y + vB2 * atB.z + vB3 * atB.w;
        #pragma unroll
        for (int m = 1; m <= 8; m <<= 1) {
            sA += __shfl_xor(sA, m, 64);
            sB += __shfl_xor(sB, m, 64);
        }
        // online softmax update, head A
        float mnA = fmaxf(mA, sA);
        float scA = __expf(mA - mnA), peA = __expf(sA - mnA);
        accA.x = accA.x * scA + peA * cxa.x;  accA.y = accA.y * scA + peA * cxa.y;
        accA.z = accA.z * scA + peA * cxa.z;  accA.w = accA.w * scA + peA * cxa.w;
        lA = lA * scA + peA;  mA = mnA;
        // head B
        float mnB = fmaxf(mB, sB);
        float scB = __expf(mB - mnB), peB = __expf(sB - mnB);
        accB.x = accB.x * scB + peB * cxb.x;  accB.y = accB.y * scB + peB * cxb.y;
        accB.z = accB.z * scB + peB * cxb.z;  accB.w = accB.w * scB + peB * cxb.w;
        lB = lB * scB + peB;  mB = mnB;
    }
    float rA = 1.f / (lA + 1e-16f), rB = 1.f / (lB + 1e-16f);
    float4 biA = *(const float4*)(bias + off);
    float4 biB = *(const float4*)(bias + off + 256);
    float4 oA = make_float4(fmaxf(accA.x * rA + biA.x, 0.f),
                            fmaxf(accA.y * rA + biA.y, 0.f),
                            fmaxf(accA.z * rA + biA.z, 0.f),
                            fmaxf(accA.w * rA + biA.w, 0.f));
    float4 oB = make_float4(fmaxf(accB.x * rB + biB.x, 0.f),
                            fmaxf(accB.y * rB + biB.y, 0.f),
                            fmaxf(accB.z * rB + biB.z, 0.f),
                            fmaxf(accB.w * rB + biB.w, 0.f));
    float4* op = (float4*)(out + (size_t)n * 512 + off);
    op[0]  = oA;      // ReLU applied (layer-1 activation)
    op[64] = oB;
}

// ------- fused GATv2 layer 2 (1 head, 64 ch): one wave per node -------
__global__ void __launch_bounds__(256) k_gat2(
    const float* __restrict__ xl, const float* __restrict__ xr,
    const float* __restrict__ att, const float* __restrict__ bias,
    const int* __restrict__ rowptr, const int* __restrict__ csr,
    float* __restrict__ out) {
    int wid = (blockIdx.x * blockDim.x + threadIdx.x) >> 6;
    int lane = threadIdx.x & 63;
    if (wid >= NN) return;
    int n = wid;
    float xrv = xr[(size_t)n * 64 + lane];
    float atv = att[lane];
    float acc = 0.f, lsum = 0.f, mmax = -1e30f;
    int p0 = rowptr[n], p1 = rowptr[n + 1];
    int deg = p1 - p0;
    float x0 = xl[(size_t)csr[p0] * 64 + lane];
    float x1 = (deg > 1) ? xl[(size_t)csr[p0 + 1] * 64 + lane] : x0;
    for (int i = 0; i < deg; i++) {
        float xs = x0;
        x0 = x1;
        if (i + 2 < deg) x1 = xl[(size_t)csr[p0 + i + 2] * 64 + lane];
        float v = xs + xrv;
        v = (v > 0.f) ? v : NEG * v;
        float sc = v * atv;
        #pragma unroll
        for (int off = 32; off > 0; off >>= 1)
            sc += __shfl_xor(sc, off, 64);
        float mn = fmaxf(mmax, sc);
        float scale = __expf(mmax - mn);
        float pe = __expf(sc - mn);
        acc = acc * scale + pe * xs;
        lsum = lsum * scale + pe;
        mmax = mn;
    }
    float o = acc / (lsum + 1e-16f) + bias[lane];
    out[(size_t)n * 64 + lane] = (o > 0.f) ? o : 0.f;   // ReLU after layer 2
}

// --- FC: out[10000,5000] = h2[10000,64] @ Wt + fc_b ---
__global__ void __launch_bounds__(256) k_fc2(
    const float* __restrict__ A, const float* __restrict__ Wt,
    const float* __restrict__ bias, float* __restrict__ C) {
    __shared__ float As[64][FC_R];
    int t = threadIdx.x;
    int r0 = blockIdx.y * FC_R;
    int c0 = blockIdx.x * 1024 + t * 4;
    {
        int r = t >> 4, kq = (t & 15) * 4;
        float4 v = *(const float4*)(A + (size_t)(r0 + r) * 64 + kq);
        As[kq + 0][r] = v.x; As[kq + 1][r] = v.y;
        As[kq + 2][r] = v.z; As[kq + 3][r] = v.w;
    }
    __syncthreads();
    float acc[FC_R][4] = {};
    #pragma unroll 4
    for (int k = 0; k < 64; k++) {
        float4 wv = *(const float4*)(Wt + (size_t)k * WT_LD + c0);
        float4 a0 = *(const float4*)&As[k][0];
        float4 a1 = *(const float4*)&As[k][4];
        float4 a2 = *(const float4*)&As[k][8];
        float4 a3 = *(const float4*)&As[k][12];
        float ar[FC_R] = {a0.x, a0.y, a0.z, a0.w, a1.x, a1.y, a1.z, a1.w,
                          a2.x, a2.y, a2.z, a2.w, a3.x, a3.y, a3.z, a3.w};
        float wr[4] = {wv.x, wv.y, wv.z, wv.w};
        #pragma unroll
        for (int r = 0; r < FC_R; r++)
            #pragma unroll
            for (int j = 0; j < 4; j++)
                acc[r][j] = fmaf(ar[r], wr[j], acc[r][j]);
    }
    if (c0 < ODIM) {   // ODIM % 4 == 0: float4 chunk fully valid or fully out
        float4 bv = *(const float4*)(bias + c0);
        #pragma unroll
        for (int r = 0; r < FC_R; r++) {
            float4 o = make_float4(acc[r][0] + bv.x, acc[r][1] + bv.y,
                                   acc[r][2] + bv.z, acc[r][3] + bv.w);
            *(float4*)&C[(size_t)(r0 + r) * ODIM + c0] = o;
        }
    }
}

extern "C" void kernel_launch(void* const* d_in, const int* in_sizes, int n_in,
                              void* d_out, int out_size, void* d_ws, size_t ws_size,
                              hipStream_t stream) {
    const float* x     = (const float*)d_in[0];
    const int*   ei    = (const int*)d_in[1];
    const float* W1l   = (const float*)d_in[2];
    const float* b1l   = (const float*)d_in[3];
    const float* W1r   = (const float*)d_in[4];
    const float* b1r   = (const float*)d_in[5];
    const float* att1  = (const float*)d_in[6];
    const float* bias1 = (const float*)d_in[7];
    const float* W2l   = (const float*)d_in[8];
    const float* b2l   = (const float*)d_in[9];
    const float* W2r   = (const float*)d_in[10];
    const float* b2r   = (const float*)d_in[11];
    const float* att2  = (const float*)d_in[12];
    const float* bias2 = (const float*)d_in[13];
    const float* fcw   = (const float*)d_in[14];
    const float* fcb   = (const float*)d_in[15];
    float* out = (float*)d_out;

    char* p = (char*)d_ws;
    auto carve = [&](size_t bytes) {
        void* r = (void*)p;
        p += (bytes + 255) & ~(size_t)255;
        return r;
    };
    int* deg    = (int*)carve((size_t)NN * 4);
    int* rowptr = (int*)carve((size_t)(NN + 1) * 4);
    int* cursor = (int*)carve((size_t)NN * 4);
    int* csr    = (int*)carve((size_t)ET * 4);
    int* flag   = (int*)carve(256);
    float* Wt  = (float*)carve((size_t)64 * WT_LD * 4);
    float* xl1 = (float*)carve((size_t)NN * 512 * 4);
    float* xr1 = (float*)carve((size_t)NN * 512 * 4);
    float* h1  = (float*)carve((size_t)NN * 512 * 4);
    _Float16* xh  = (_Float16*)carve((size_t)NN * 512 * 2);
    _Float16* xlo = (_Float16*)carve((size_t)NN * 512 * 2);
    _Float16* w1lh = (_Float16*)carve((size_t)512 * 512 * 2);
    _Float16* w1ll = (_Float16*)carve((size_t)512 * 512 * 2);
    _Float16* w1rh = (_Float16*)carve((size_t)512 * 512 * 2);
    _Float16* w1rl = (_Float16*)carve((size_t)512 * 512 * 2);
    _Float16* w2lh = (_Float16*)carve((size_t)64 * 512 * 2);
    _Float16* w2ll = (_Float16*)carve((size_t)64 * 512 * 2);
    _Float16* w2rh = (_Float16*)carve((size_t)64 * 512 * 2);
    _Float16* w2rl = (_Float16*)carve((size_t)64 * 512 * 2);
    float* xl2 = xl1;                            // aliases: xl1/xr1 dead after k_gat1
    float* xr2 = xl1 + (size_t)NN * 64;
    float* h2  = xl1 + (size_t)NN * 128;

    // prep (transpose + deg init + format detect), then CSR by destination
    k_prep<<<PREPB, 256, 0, stream>>>(ei, flag, deg, fcw, Wt);
    k_hist<<<(NE + 255) / 256, 256, 0, stream>>>(ei, flag, deg);
    k_scan<<<1, 1024, 0, stream>>>(deg, rowptr, cursor);
    k_scatter<<<(ET + 255) / 256, 256, 0, stream>>>(ei, flag, cursor, csr);

    // layer 1: fp16-split + MFMA pair GEMM (3-pass hi/lo)
    int nx = NN * 512 / 8, nw1 = 512 * 512 / 8;
    k_split3<<<(nx + 2 * nw1 + 255) / 256, 256, 0, stream>>>(
        x, xh, xlo, nx, W1l, w1lh, w1ll, nw1, W1r, w1rh, w1rl, nw1);
    dim3 g1(8, (NN + 127) / 128);
    k_gemm_mfma<<<g1, 256, 0, stream>>>(xh, xlo, w1lh, w1ll, w1rh, w1rl,
                                        b1l, b1r, xl1, xr1, NN, 8);
    k_gat1<<<(NN * 64 + 255) / 256, 256, 0, stream>>>(xl1, xr1, att1, bias1, rowptr, csr, h1);

    // layer 2: split h1 (reuse xh/xlo) + same MFMA kernel, nbpm=1
    int nw2 = 64 * 512 / 8;
    k_split3<<<(nx + 2 * nw2 + 255) / 256, 256, 0, stream>>>(
        h1, xh, xlo, nx, W2l, w2lh, w2ll, nw2, W2r, w2rh, w2rl, nw2);
    dim3 g2(1, (NN + 127) / 128);
    k_gemm_mfma<<<g2, 256, 0, stream>>>(xh, xlo, w2lh, w2ll, w2rh, w2rl,
                                        b2l, b2r, xl2, xr2, NN, 1);
    k_gat2<<<(NN * 64 + 255) / 256, 256, 0, stream>>>(xl2, xr2, att2, bias2, rowptr, csr, h2);

    // FC head: 5 col-blocks x 625 row-blocks
    dim3 g3((ODIM + 1023) / 1024, NN / FC_R);
    k_fc2<<<g3, 256, 0, stream>>>(h2, Wt, fcb, out);
}